// Round 18
// baseline (708.063 us; speedup 1.0000x reference)
//
#include <hip/hip_runtime.h>

typedef unsigned short u16;
typedef unsigned char u8;
typedef unsigned int u32;
typedef long i64;
typedef __attribute__((ext_vector_type(8))) short bf16x8;
typedef __attribute__((ext_vector_type(4))) float f32x4;
typedef __attribute__((ext_vector_type(4))) u16 u16x4;

__device__ __forceinline__ u16 f2bf(float f) {
  u32 u = __builtin_bit_cast(u32, f);
  return (u16)((u + 0x7FFFu + ((u >> 16) & 1u)) >> 16);
}
__device__ __forceinline__ u8 f2fp8(float f) {
  int w = __builtin_amdgcn_cvt_pk_fp8_f32(f, 0.f, 0, false);
  return (u8)(w & 0xff);
}

__device__ __forceinline__ f32x4 mfma16(bf16x8 a, bf16x8 b, f32x4 c) {
  return __builtin_amdgcn_mfma_f32_16x16x32_bf16(a, b, c, 0, 0, 0);
}
__device__ __forceinline__ f32x4 mfma16f8(i64 a, i64 b, f32x4 c) {
  return __builtin_amdgcn_mfma_f32_16x16x32_fp8_fp8(a, b, c, 0, 0, 0);
}

__device__ __forceinline__ void gload16(const void* g, void* l) {
  __builtin_amdgcn_global_load_lds(
      (const __attribute__((address_space(1))) unsigned int*)g,
      (__attribute__((address_space(3))) unsigned int*)l, 16, 0, 0);
}

__device__ __forceinline__ u32 cvtpk(float lo, float hi) {
  u32 r;
  asm volatile("v_cvt_pk_bf16_f32 %0, %1, %2" : "=v"(r) : "v"(lo), "v"(hi));
  return r;
}

// ---------------- pack kernels ----------------

__global__ void pack_x_kernel(const float* __restrict__ x, u16* __restrict__ xb) {
  const int i = blockIdx.x * 256 + threadIdx.x;
  const float4 v = ((const float4*)x)[i];
  u16x4 o;
  o[0] = f2bf(v.x); o[1] = f2bf(v.y); o[2] = f2bf(v.z); o[3] = f2bf(v.w);
  ((u16x4*)xb)[i] = o;
}

// W: [512][4096] col = k*8+h  ->  Wp: [h*512+k][dd]  (tiled LDS transpose)
__global__ void pack_wqkv_t(const float* __restrict__ W, u16* __restrict__ Wp) {
  __shared__ u16 tile[64][72];
  const int t = threadIdx.x;
  const int c0 = blockIdx.x * 64, dd0 = blockIdx.y * 64;
#pragma unroll
  for (int s = 0; s < 4; ++s) {
    const int r = s * 16 + (t >> 4);
    const int q = (t & 15) * 4;
    const float4 v = *(const float4*)&W[(size_t)(dd0 + r) * 4096 + c0 + q];
    tile[r][q + 0] = f2bf(v.x); tile[r][q + 1] = f2bf(v.y);
    tile[r][q + 2] = f2bf(v.z); tile[r][q + 3] = f2bf(v.w);
  }
  __syncthreads();
#pragma unroll
  for (int s = 0; s < 4; ++s) {
    const int cl = s * 16 + (t >> 4);
    const int u = t & 15;
    const int cg = c0 + cl;
    const int orow = (cg & 7) * 512 + (cg >> 3);
    u16x4 o;
#pragma unroll
    for (int i = 0; i < 4; ++i) o[i] = tile[u * 4 + i][cl];
    *(u16x4*)&Wp[(size_t)orow * 512 + dd0 + u * 4] = o;
  }
}

// Wo: [4096][512] -> Wot: [n=512][k=4096]
__global__ void pack_wo_t(const float* __restrict__ W, u16* __restrict__ Wp) {
  __shared__ u16 tile[64][72];
  const int t = threadIdx.x;
  const int k0 = blockIdx.x * 64, n0 = blockIdx.y * 64;
#pragma unroll
  for (int s = 0; s < 4; ++s) {
    const int r = s * 16 + (t >> 4);
    const int q = (t & 15) * 4;
    const float4 v = *(const float4*)&W[(size_t)(k0 + r) * 512 + n0 + q];
    tile[r][q + 0] = f2bf(v.x); tile[r][q + 1] = f2bf(v.y);
    tile[r][q + 2] = f2bf(v.z); tile[r][q + 3] = f2bf(v.w);
  }
  __syncthreads();
#pragma unroll
  for (int s = 0; s < 4; ++s) {
    const int cl = s * 16 + (t >> 4);
    const int u = t & 15;
    u16x4 o;
#pragma unroll
    for (int i = 0; i < 4; ++i) o[i] = tile[u * 4 + i][cl];
    *(u16x4*)&Wp[(size_t)(n0 + cl) * 4096 + k0 + u * 4] = o;
  }
}

// ---------------- GEMM: C[M][N] = A[M][Kd] * B[N][Kd]^T ----------------
// MODE 0: fp8 -> [bh][t][d] (*scale)                       (Q)      BN=128
// MODE 1: bf16 transposed -> Vt [bh][d][t]                 (V)      BN=128
// MODE 2: fp32 + bias -> [row][512]                        (out)    BN=64
// MODE 3: fp8 K4-tiled [bh][t/32][k/16][t&31][16B] (*scale)(K)      BN=128

template <int MODE, int BN>
__global__ __launch_bounds__(256, 2) void gemm_bf16(
    const u16* __restrict__ A, const u16* __restrict__ B,
    void* __restrict__ Cout, const float* __restrict__ bias,
    int Kd, float scale) {
  constexpr int JT = BN / 32;
  __shared__ u16 Al[128 * 64];
  __shared__ u16 Bl[BN * 64];
  const int tid = threadIdx.x;
  const int lane = tid & 63;
  const int w = tid >> 6, wm = w >> 1, wn = w & 1;
  const int l15 = lane & 15, lg = lane >> 4;
  const int m0 = blockIdx.y * 128, n0 = blockIdx.x * BN;

  f32x4 acc[4][JT];
#pragma unroll
  for (int i = 0; i < 4; ++i)
#pragma unroll
    for (int j = 0; j < JT; ++j) acc[i][j] = {};

  const int nk = Kd >> 6;
  for (int kt = 0; kt < nk; ++kt) {
    __syncthreads();
    const int k0 = kt << 6;
#pragma unroll
    for (int s = 0; s < 4; ++s) {
      const int chunk = s * 256 + tid;
      const int row = chunk >> 3, c = chunk & 7;
      const int cs = c ^ (row & 7);
      gload16(A + (size_t)(m0 + row) * Kd + k0 + cs * 8, &Al[chunk * 8]);
    }
#pragma unroll
    for (int s = 0; s < BN / 32; ++s) {
      const int chunk = s * 256 + tid;
      const int row = chunk >> 3, c = chunk & 7;
      const int cs = c ^ (row & 7);
      gload16(B + (size_t)(n0 + row) * Kd + k0 + cs * 8, &Bl[chunk * 8]);
    }
    __syncthreads();
#pragma unroll
    for (int kk = 0; kk < 2; ++kk) {
      bf16x8 af[4], bfr[JT];
      const int ch = kk * 4 + lg;
#pragma unroll
      for (int i = 0; i < 4; ++i) {
        const int ar = wm * 64 + i * 16 + l15;
        af[i] = *(const bf16x8*)&Al[ar * 64 + ((ch ^ (ar & 7)) * 8)];
      }
#pragma unroll
      for (int j = 0; j < JT; ++j) {
        const int br = wn * (BN / 2) + j * 16 + l15;
        bfr[j] = *(const bf16x8*)&Bl[br * 64 + ((ch ^ (br & 7)) * 8)];
      }
#pragma unroll
      for (int i = 0; i < 4; ++i)
#pragma unroll
        for (int j = 0; j < JT; ++j)
          acc[i][j] = mfma16(af[i], bfr[j], acc[i][j]);
    }
  }

#pragma unroll
  for (int i = 0; i < 4; ++i) {
    const int gr0 = m0 + wm * 64 + i * 16 + lg * 4;
#pragma unroll
    for (int j = 0; j < JT; ++j) {
      const int gc = n0 + wn * (BN / 2) + j * 16 + l15;
      if constexpr (MODE == 0) {
        u8* O = (u8*)Cout;
        const int h = gc >> 9, d = gc & 511;
#pragma unroll
        for (int r = 0; r < 4; ++r) {
          const int grr = gr0 + r;
          const int bb = grr >> 11, t = grr & 2047;
          O[((size_t)((bb * 8 + h) * 2048 + t) << 9) + d] = f2fp8(acc[i][j][r] * scale);
        }
      } else if constexpr (MODE == 1) {
        u16* O = (u16*)Cout;
        const int h = gc >> 9, d = gc & 511;
        const int bb = gr0 >> 11, t = gr0 & 2047;
        u16x4 pk;
#pragma unroll
        for (int r = 0; r < 4; ++r) pk[r] = f2bf(acc[i][j][r]);
        *(u16x4*)&O[((size_t)((bb * 8 + h) * 512 + d) << 11) + t] = pk;
      } else if constexpr (MODE == 3) {
        u8* O = (u8*)Cout;
        const int h = gc >> 9, k = gc & 511;
#pragma unroll
        for (int r = 0; r < 4; ++r) {
          const int grr = gr0 + r;
          const int bb = grr >> 11, t = grr & 2047;
          O[((((size_t)(bb * 8 + h) * 64 + (t >> 5)) * 32 + (k >> 4)) * 32 + (t & 31)) * 16 +
            (k & 15)] = f2fp8(acc[i][j][r] * scale);
        }
      } else {
        float* O = (float*)Cout;
        const float bv = bias[gc];
#pragma unroll
        for (int r = 0; r < 4; ++r)
          O[(size_t)(gr0 + r) * 512 + gc] = acc[i][j][r] + bv;
      }
    }
  }
}

// ---------------- flash attention v18: kv-split, 4-wave blocks, K in regs, 2 blk/CU ----
// Q fp8: [bh][2048][512]B; K4 fp8 tiled: [bh][64][32][32][16B]; Vt bf16: [bh][512][2048];
// Og bf16: [bb*2048+t][h*512+d]
// block = 4 waves (256 thr) = 2 pairs; pair owns 32 q rows (64 q/block); 32 q-tiles/bh.
// Wave (pr,whalf): QKT for kv rows whalf*16..+15 (full k=512, K from REGISTERS via K4);
// PV for d-half whalf*256..+255 over all 32 kv (P via bf16 LDS).
// KV block 32, 64 steps. LDS = Vt dbuf 64K + P 4K + Lsum .5K = 68.6K -> 2 blocks/CU
// (two independent barrier domains per CU; regs ~252/wave x 8 waves = CU cap).
// Pacing: stage V(t+1) at step START; kf(t+1) prefetch after QKT; mid lgkm barrier (P);
// end vmcnt(0)+lgkm(0) barrier. Constant-m softmax (r14-verified).

__global__ __launch_bounds__(256, 2) void attn_kernel(
    const u8* __restrict__ Qg, const u8* __restrict__ K4g,
    const u16* __restrict__ Vtg, u16* __restrict__ Og, int nbh_pxcd) {
  __shared__ u16 Vt_lds[2][512 * 32];  // [buf][d][kv]  8-u16 chunk swz: c ^ ((d>>1)&3)
  __shared__ u16 P_lds[2][2][16][32];  // [pair][qtile][q][kv] bf16
  __shared__ float Lsum[4][2][16];

  const int tid = threadIdx.x;
  const int lane = tid & 63;
  const int w = tid >> 6;               // 0..3
  const int pr = w >> 1, whalf = w & 1; // pair 0..1, half 0..1
  const int l15 = lane & 15, lg = lane >> 4;

  const int bid = blockIdx.x;
  const int x8 = bid & 7, rest = bid >> 3;
  const int qt = rest & 31;                    // 32 q-tiles of 64 rows
  const int bh = x8 * nbh_pxcd + (rest >> 5);

  const u8* Qb = Qg + (size_t)bh * 2048 * 512;
  const u8* K4b = K4g + (size_t)bh * 2048 * 512;
  const u16* Vb = Vtg + (size_t)bh * 2048 * 512;

  // Q fp8 fragments, full k: qf8[qtile][cc] covers k = cc*32 + lg*8 .. +7
  i64 qf8[2][16];
#pragma unroll
  for (int qtile = 0; qtile < 2; ++qtile) {
    const int qrow = qt * 64 + pr * 32 + qtile * 16 + l15;
    const u8* qp = Qb + (size_t)qrow * 512 + lg * 8;
#pragma unroll
    for (int cc = 0; cc < 16; ++cc) qf8[qtile][cc] = *(const i64*)(qp + cc * 32);
  }

  // per-lane K4 offset inside a tile (16KB): fragment cc at klane + cc*1024
  // K A-fragment: row kv = whalf*16 + l15, k = cc*32 + lg*8
  const int klane = (lg >> 1) * 512 + (whalf * 16 + l15) * 16 + (lg & 1) * 8;

  f32x4 acc[2][16];
#pragma unroll
  for (int i = 0; i < 2; ++i)
#pragma unroll
    for (int j = 0; j < 16; ++j) acc[i][j] = {};
  float lsum0 = 0.f, lsum1 = 0.f;

#define STAGE_V(tile, buf)                                                    \
  {                                                                           \
    _Pragma("unroll") for (int s_ = 0; s_ < 8; ++s_) {                        \
      const int chunk = s_ * 256 + tid;                                       \
      const int row = chunk >> 2, c_ = chunk & 3;                             \
      const int cs = c_ ^ ((row >> 1) & 3);                                   \
      gload16(Vb + (size_t)row * 2048 + (tile) * 32 + cs * 8,                 \
              &Vt_lds[buf][chunk * 8]);                                       \
    }                                                                         \
  }

  // -------- prologue: stage V(0), preload K(0) frags --------
  STAGE_V(0, 0);
  i64 kf[16];
  {
    const u8* kp = K4b + klane;
#pragma unroll
    for (int cc = 0; cc < 16; ++cc) kf[cc] = *(const i64*)(kp + cc * 1024);
  }
  asm volatile("s_waitcnt vmcnt(0)" ::: "memory");
  __builtin_amdgcn_s_barrier();

  for (int t = 0; t < 64; ++t) {
    const int cur = t & 1;

    // stage V(t+1) at step START (in flight across whole step; convoy pacing)
    if (t < 63) STAGE_V(t + 1, cur ^ 1);

    // QKT(t): complete logits S[kv 16][q 32], full k; K from registers
    f32x4 s0a = {}, s0b = {}, s1a = {}, s1b = {};
#pragma unroll
    for (int cc = 0; cc < 8; ++cc) {
      s0a = mfma16f8(kf[cc], qf8[0][cc], s0a);
      s1a = mfma16f8(kf[cc], qf8[1][cc], s1a);
    }
#pragma unroll
    for (int cc = 8; cc < 16; ++cc) {
      s0b = mfma16f8(kf[cc], qf8[0][cc], s0b);
      s1b = mfma16f8(kf[cc], qf8[1][cc], s1b);
    }

    // kf prefetch (t+1) -- WAR after QKT; drains at end barrier
    if (t < 63) {
      const u8* kp = K4b + ((size_t)(t + 1) << 14) + klane;
#pragma unroll
      for (int cc = 0; cc < 16; ++cc) kf[cc] = *(const i64*)(kp + cc * 1024);
    }

    // constant-m softmax: p = exp(s)
    f32x4 s0, s1;
#pragma unroll
    for (int r = 0; r < 4; ++r) {
      s0[r] = __expf(s0a[r] + s0b[r]);
      lsum0 += s0[r];
      s1[r] = __expf(s1a[r] + s1b[r]);
      lsum1 += s1[r];
    }

    // write P(t) bf16: lane holds P[kv = whalf*16 + lg*4 + r][q = qtile*16 + l15]
    {
      const int kvbase = whalf * 16 + lg * 4;
      u32 a0 = cvtpk(s0[0], s0[1]), a1 = cvtpk(s0[2], s0[3]);
      u32 b0 = cvtpk(s1[0], s1[1]), b1 = cvtpk(s1[2], s1[3]);
      u16x4 pk0 = __builtin_bit_cast(u16x4, ((unsigned long long)a1 << 32) | a0);
      u16x4 pk1 = __builtin_bit_cast(u16x4, ((unsigned long long)b1 << 32) | b0);
      *(u16x4*)&P_lds[pr][0][l15][kvbase] = pk0;
      *(u16x4*)&P_lds[pr][1][l15][kvbase] = pk1;
    }
    asm volatile("s_waitcnt lgkmcnt(0)" ::: "memory");
    __builtin_amdgcn_s_barrier();  // mid: P visible pair-wide

    // PV(t): O^T[d 16-tiles][q 16x2] over all 32 kv; A=V rows, B=P
    {
      bf16x8 pfr0 = *(const bf16x8*)&P_lds[pr][0][l15][lg * 8];
      bf16x8 pfr1 = *(const bf16x8*)&P_lds[pr][1][l15][lg * 8];
#pragma unroll
      for (int dtile = 0; dtile < 16; ++dtile) {
        const int drow = whalf * 256 + dtile * 16 + l15;
        const int pos = lg ^ ((drow >> 1) & 3);
        bf16x8 vf = *(const bf16x8*)&Vt_lds[cur][drow * 32 + pos * 8];
        acc[0][dtile] = mfma16(vf, pfr0, acc[0][dtile]);
        acc[1][dtile] = mfma16(vf, pfr1, acc[1][dtile]);
      }
    }

    // end of step: staging + kf prefetch complete; P/V reads retired
    asm volatile("s_waitcnt vmcnt(0) lgkmcnt(0)" ::: "memory");
    __builtin_amdgcn_s_barrier();
  }

  // -------- finalize: reduce lsum across lg groups, then across pair --------
  lsum0 += __shfl_xor(lsum0, 16, 64);
  lsum0 += __shfl_xor(lsum0, 32, 64);
  lsum1 += __shfl_xor(lsum1, 16, 64);
  lsum1 += __shfl_xor(lsum1, 32, 64);
  if (lane < 16) {
    Lsum[w][0][l15] = lsum0;
    Lsum[w][1][l15] = lsum1;
  }
  __syncthreads();
  const float inv0 = 1.0f / (Lsum[w][0][l15] + Lsum[w ^ 1][0][l15]);
  const float inv1 = 1.0f / (Lsum[w][1][l15] + Lsum[w ^ 1][1][l15]);

  const int bb = bh >> 3, h = bh & 7;
#pragma unroll
  for (int qtile = 0; qtile < 2; ++qtile) {
    const float inv = qtile ? inv1 : inv0;
    const int q = qt * 64 + pr * 32 + qtile * 16 + l15;
    u16* orow_p = Og + (size_t)(bb * 2048 + q) * 4096 + h * 512 + whalf * 256;
#pragma unroll
    for (int dtile = 0; dtile < 16; ++dtile) {
      u16x4 pk;
#pragma unroll
      for (int r = 0; r < 4; ++r) pk[r] = f2bf(acc[qtile][dtile][r] * inv);
      *(u16x4*)(orow_p + dtile * 16 + lg * 4) = pk;
    }
  }
#undef STAGE_V
}

// ---------------- launcher ----------------
// Per-batch: Q 8 + K 8 + Vt 16 + Og 16 = 48 MB.  ws need = 24 + 48*BB:
// BB=4 -> 216 MB, BB=2 -> 120 MB, BB=1 -> 72 MB.

extern "C" void kernel_launch(void* const* d_in, const int* in_sizes, int n_in,
                              void* d_out, int out_size, void* d_ws, size_t ws_size,
                              hipStream_t stream) {
  const float* x = (const float*)d_in[0];
  const float* Wq = (const float*)d_in[1];
  const float* Wk = (const float*)d_in[2];
  const float* Wv = (const float*)d_in[3];
  const float* Wo = (const float*)d_in[4];
  const float* bo = (const float*)d_in[5];
  float* out = (float*)d_out;

  const size_t MB = 1ull << 20;
  int BB;
  if (ws_size >= 216 * MB) BB = 4;
  else if (ws_size >= 120 * MB) BB = 2;
  else BB = 1;

  char* ws = (char*)d_ws;
  u16* xb  = (u16*)(ws);
  u16* Wqp = (u16*)(ws + 8 * MB);
  u16* Wkp = (u16*)(ws + 12 * MB);
  u16* Wvp = (u16*)(ws + 16 * MB);
  u16* Wot = (u16*)(ws + 20 * MB);
  u8*  Qg  = (u8*)(ws + 24 * MB);
  u8*  Kg  = (u8*)(ws + (24 + 8 * (size_t)BB) * MB);
  u16* Vtg = (u16*)(ws + (24 + 16 * (size_t)BB) * MB);
  u16* Og  = (u16*)(ws + (24 + 32 * (size_t)BB) * MB);

  pack_x_kernel<<<dim3(4096), dim3(256), 0, stream>>>(x, xb);
  pack_wqkv_t<<<dim3(64, 8), dim3(256), 0, stream>>>(Wq, Wqp);
  pack_wqkv_t<<<dim3(64, 8), dim3(256), 0, stream>>>(Wk, Wkp);
  pack_wqkv_t<<<dim3(64, 8), dim3(256), 0, stream>>>(Wv, Wvp);
  pack_wo_t<<<dim3(64, 8), dim3(256), 0, stream>>>(Wo, Wot);

  const float qk_scale = 0.21022410381342865f;  // 1 / 512^0.25

  const int nchunk = 4 / BB;
  for (int c = 0; c < nchunk; ++c) {
    const u16* Ax = xb + (size_t)c * BB * 2048 * 512;
    gemm_bf16<0, 128><<<dim3(32, BB * 16), dim3(256), 0, stream>>>(Ax, Wqp, (void*)Qg, nullptr, 512, qk_scale);
    gemm_bf16<3, 128><<<dim3(32, BB * 16), dim3(256), 0, stream>>>(Ax, Wkp, (void*)Kg, nullptr, 512, qk_scale);
    gemm_bf16<1, 128><<<dim3(32, BB * 16), dim3(256), 0, stream>>>(Ax, Wvp, (void*)Vtg, nullptr, 512, 1.0f);

    attn_kernel<<<dim3(32 * BB * 8), dim3(256), 0, stream>>>(Qg, Kg, Vtg, Og, BB);

    gemm_bf16<2, 64><<<dim3(8, BB * 16), dim3(256), 0, stream>>>(
        Og, Wot, (void*)(out + (size_t)c * BB * 2048 * 512), bo, 4096, 1.0f);
  }
}

// Round 19
// 508.183 us; speedup vs baseline: 1.3933x; 1.3933x over previous
//
#include <hip/hip_runtime.h>

typedef unsigned short u16;
typedef unsigned char u8;
typedef unsigned int u32;
typedef long i64;
typedef __attribute__((ext_vector_type(8))) short bf16x8;
typedef __attribute__((ext_vector_type(4))) float f32x4;
typedef __attribute__((ext_vector_type(4))) u16 u16x4;

__device__ __forceinline__ u16 f2bf(float f) {
  u32 u = __builtin_bit_cast(u32, f);
  return (u16)((u + 0x7FFFu + ((u >> 16) & 1u)) >> 16);
}
__device__ __forceinline__ u8 f2fp8(float f) {
  int w = __builtin_amdgcn_cvt_pk_fp8_f32(f, 0.f, 0, false);
  return (u8)(w & 0xff);
}

__device__ __forceinline__ f32x4 mfma16(bf16x8 a, bf16x8 b, f32x4 c) {
  return __builtin_amdgcn_mfma_f32_16x16x32_bf16(a, b, c, 0, 0, 0);
}
__device__ __forceinline__ f32x4 mfma16f8(i64 a, i64 b, f32x4 c) {
  return __builtin_amdgcn_mfma_f32_16x16x32_fp8_fp8(a, b, c, 0, 0, 0);
}

__device__ __forceinline__ void gload16(const void* g, void* l) {
  __builtin_amdgcn_global_load_lds(
      (const __attribute__((address_space(1))) unsigned int*)g,
      (__attribute__((address_space(3))) unsigned int*)l, 16, 0, 0);
}

__device__ __forceinline__ u32 cvtpk(float lo, float hi) {
  u32 r;
  asm volatile("v_cvt_pk_bf16_f32 %0, %1, %2" : "=v"(r) : "v"(lo), "v"(hi));
  return r;
}

// ---------------- pack kernels ----------------

__global__ void pack_x_kernel(const float* __restrict__ x, u16* __restrict__ xb) {
  const int i = blockIdx.x * 256 + threadIdx.x;
  const float4 v = ((const float4*)x)[i];
  u16x4 o;
  o[0] = f2bf(v.x); o[1] = f2bf(v.y); o[2] = f2bf(v.z); o[3] = f2bf(v.w);
  ((u16x4*)xb)[i] = o;
}

// W: [512][4096] col = k*8+h  ->  Wp: [h*512+k][dd]  (tiled LDS transpose)
__global__ void pack_wqkv_t(const float* __restrict__ W, u16* __restrict__ Wp) {
  __shared__ u16 tile[64][72];
  const int t = threadIdx.x;
  const int c0 = blockIdx.x * 64, dd0 = blockIdx.y * 64;
#pragma unroll
  for (int s = 0; s < 4; ++s) {
    const int r = s * 16 + (t >> 4);
    const int q = (t & 15) * 4;
    const float4 v = *(const float4*)&W[(size_t)(dd0 + r) * 4096 + c0 + q];
    tile[r][q + 0] = f2bf(v.x); tile[r][q + 1] = f2bf(v.y);
    tile[r][q + 2] = f2bf(v.z); tile[r][q + 3] = f2bf(v.w);
  }
  __syncthreads();
#pragma unroll
  for (int s = 0; s < 4; ++s) {
    const int cl = s * 16 + (t >> 4);
    const int u = t & 15;
    const int cg = c0 + cl;
    const int orow = (cg & 7) * 512 + (cg >> 3);
    u16x4 o;
#pragma unroll
    for (int i = 0; i < 4; ++i) o[i] = tile[u * 4 + i][cl];
    *(u16x4*)&Wp[(size_t)orow * 512 + dd0 + u * 4] = o;
  }
}

// Wo: [4096][512] -> Wot: [n=512][k=4096]
__global__ void pack_wo_t(const float* __restrict__ W, u16* __restrict__ Wp) {
  __shared__ u16 tile[64][72];
  const int t = threadIdx.x;
  const int k0 = blockIdx.x * 64, n0 = blockIdx.y * 64;
#pragma unroll
  for (int s = 0; s < 4; ++s) {
    const int r = s * 16 + (t >> 4);
    const int q = (t & 15) * 4;
    const float4 v = *(const float4*)&W[(size_t)(k0 + r) * 512 + n0 + q];
    tile[r][q + 0] = f2bf(v.x); tile[r][q + 1] = f2bf(v.y);
    tile[r][q + 2] = f2bf(v.z); tile[r][q + 3] = f2bf(v.w);
  }
  __syncthreads();
#pragma unroll
  for (int s = 0; s < 4; ++s) {
    const int cl = s * 16 + (t >> 4);
    const int u = t & 15;
    u16x4 o;
#pragma unroll
    for (int i = 0; i < 4; ++i) o[i] = tile[u * 4 + i][cl];
    *(u16x4*)&Wp[(size_t)(n0 + cl) * 4096 + k0 + u * 4] = o;
  }
}

// ---------------- GEMM: C[M][N] = A[M][Kd] * B[N][Kd]^T ----------------
// 1D grid + T1 XCD-chunked decode (bijective; grid % 8 == 0).
// MODE 0: fp8 -> [bh][t][d] (*scale)            (Q, K)   BN=128
// MODE 1: bf16 transposed -> Vt [bh][d][t]      (V)      BN=128
// MODE 2: fp32 + bias -> [row][512]             (out)    BN=64

template <int MODE, int BN>
__global__ __launch_bounds__(256, 2) void gemm_bf16(
    const u16* __restrict__ A, const u16* __restrict__ B,
    void* __restrict__ Cout, const float* __restrict__ bias,
    int Kd, float scale, int ntn) {
  constexpr int JT = BN / 32;
  __shared__ u16 Al[128 * 64];
  __shared__ u16 Bl[BN * 64];
  const int tid = threadIdx.x;
  const int lane = tid & 63;
  const int w = tid >> 6, wm = w >> 1, wn = w & 1;
  const int l15 = lane & 15, lg = lane >> 4;

  // T1: XCD-chunked block remap (each XCD gets a contiguous band of tiles)
  const int cpx = gridDim.x >> 3;
  const int wgid = (blockIdx.x & 7) * cpx + (blockIdx.x >> 3);
  const int m0 = (wgid / ntn) * 128, n0 = (wgid % ntn) * BN;

  f32x4 acc[4][JT];
#pragma unroll
  for (int i = 0; i < 4; ++i)
#pragma unroll
    for (int j = 0; j < JT; ++j) acc[i][j] = {};

  const int nk = Kd >> 6;
  for (int kt = 0; kt < nk; ++kt) {
    __syncthreads();
    const int k0 = kt << 6;
#pragma unroll
    for (int s = 0; s < 4; ++s) {
      const int chunk = s * 256 + tid;
      const int row = chunk >> 3, c = chunk & 7;
      const int cs = c ^ (row & 7);
      gload16(A + (size_t)(m0 + row) * Kd + k0 + cs * 8, &Al[chunk * 8]);
    }
#pragma unroll
    for (int s = 0; s < BN / 32; ++s) {
      const int chunk = s * 256 + tid;
      const int row = chunk >> 3, c = chunk & 7;
      const int cs = c ^ (row & 7);
      gload16(B + (size_t)(n0 + row) * Kd + k0 + cs * 8, &Bl[chunk * 8]);
    }
    __syncthreads();
#pragma unroll
    for (int kk = 0; kk < 2; ++kk) {
      bf16x8 af[4], bfr[JT];
      const int ch = kk * 4 + lg;
#pragma unroll
      for (int i = 0; i < 4; ++i) {
        const int ar = wm * 64 + i * 16 + l15;
        af[i] = *(const bf16x8*)&Al[ar * 64 + ((ch ^ (ar & 7)) * 8)];
      }
#pragma unroll
      for (int j = 0; j < JT; ++j) {
        const int br = wn * (BN / 2) + j * 16 + l15;
        bfr[j] = *(const bf16x8*)&Bl[br * 64 + ((ch ^ (br & 7)) * 8)];
      }
#pragma unroll
      for (int i = 0; i < 4; ++i)
#pragma unroll
        for (int j = 0; j < JT; ++j)
          acc[i][j] = mfma16(af[i], bfr[j], acc[i][j]);
    }
  }

#pragma unroll
  for (int i = 0; i < 4; ++i) {
    const int gr0 = m0 + wm * 64 + i * 16 + lg * 4;
#pragma unroll
    for (int j = 0; j < JT; ++j) {
      const int gc = n0 + wn * (BN / 2) + j * 16 + l15;
      if constexpr (MODE == 0) {
        u8* O = (u8*)Cout;
        const int h = gc >> 9, d = gc & 511;
#pragma unroll
        for (int r = 0; r < 4; ++r) {
          const int grr = gr0 + r;
          const int bb = grr >> 11, t = grr & 2047;
          O[((size_t)((bb * 8 + h) * 2048 + t) << 9) + d] = f2fp8(acc[i][j][r] * scale);
        }
      } else if constexpr (MODE == 1) {
        u16* O = (u16*)Cout;
        const int h = gc >> 9, d = gc & 511;
        const int bb = gr0 >> 11, t = gr0 & 2047;
        u16x4 pk;
#pragma unroll
        for (int r = 0; r < 4; ++r) pk[r] = f2bf(acc[i][j][r]);
        *(u16x4*)&O[((size_t)((bb * 8 + h) * 512 + d) << 11) + t] = pk;
      } else {
        float* O = (float*)Cout;
        const float bv = bias[gc];
#pragma unroll
        for (int r = 0; r < 4; ++r)
          O[(size_t)(gr0 + r) * 512 + gc] = acc[i][j][r] + bv;
      }
    }
  }
}

// ---------------- flash attention v17 (best measured): kv-split + PV-lag ----------------
// Q,K fp8: [bh][2048][512]B; Vt bf16: [bh][512][2048]; Og bf16: [bb*2048+t][h*512+d]
// block = 8 waves = 4 pairs; pair owns 32 q rows (128 q/block).
// Wave (pr,whalf): QKT for kv rows whalf*16..+15 (full k=512 -> complete logits);
// PV for d-half whalf*256..+255 over all 32 kv of the LAGGED tile (t-1).
// KV block 32, 64 steps. LDS = K8 dbuf 32K + V3 tribuf 96K + P parity-dbuf 16K + L 1K.
// ONE barrier per step (end: vmcnt(0)+lgkm(0)). Constant-m softmax.

__global__ __launch_bounds__(512, 2) void attn_kernel(
    const u8* __restrict__ Qg, const u8* __restrict__ Kg,
    const u16* __restrict__ Vtg, u16* __restrict__ Og, int nbh_pxcd) {
  __shared__ u8 K8[2][32 * 512];
  __shared__ u16 V3[3][512 * 32];
  __shared__ u16 P_lds[2][4][2][16][32];
  __shared__ float Lsum[8][2][16];

  const int tid = threadIdx.x;
  const int lane = tid & 63;
  const int w = tid >> 6;
  const int pr = w >> 1, whalf = w & 1;
  const int l15 = lane & 15, lg = lane >> 4;

  const int bid = blockIdx.x;
  const int x8 = bid & 7, rest = bid >> 3;
  const int qt = rest & 15;
  const int bh = x8 * nbh_pxcd + (rest >> 4);

  const u8* Qb = Qg + (size_t)bh * 2048 * 512;
  const u8* Kb = Kg + (size_t)bh * 2048 * 512;
  const u16* Vb = Vtg + (size_t)bh * 2048 * 512;

  i64 qf8[2][16];
#pragma unroll
  for (int qtile = 0; qtile < 2; ++qtile) {
    const int qrow = qt * 128 + pr * 32 + qtile * 16 + l15;
    const u8* qp = Qb + (size_t)qrow * 512 + lg * 8;
#pragma unroll
    for (int cc = 0; cc < 16; ++cc) qf8[qtile][cc] = *(const i64*)(qp + cc * 32);
  }

  f32x4 acc[2][16];
#pragma unroll
  for (int i = 0; i < 2; ++i)
#pragma unroll
    for (int j = 0; j < 16; ++j) acc[i][j] = {};
  float lsum0 = 0.f, lsum1 = 0.f;

  const int krow = whalf * 16 + l15;
  const int kswz = (krow & 15) << 1;

#define STAGE_K8(tile, buf)                                                   \
  {                                                                           \
    _Pragma("unroll") for (int s_ = 0; s_ < 2; ++s_) {                        \
      const int ch = s_ * 512 + tid;                                          \
      const int row = ch >> 5, p_ = ch & 31;                                  \
      const int ps = p_ ^ ((row & 15) << 1);                                  \
      gload16(Kb + (size_t)((tile) * 32 + row) * 512 + ps * 16,               \
              &K8[buf][ch * 16]);                                             \
    }                                                                         \
  }
#define STAGE_V(tile, buf)                                                    \
  {                                                                           \
    _Pragma("unroll") for (int s_ = 0; s_ < 4; ++s_) {                        \
      const int chunk = s_ * 512 + tid;                                       \
      const int row = chunk >> 2, c_ = chunk & 3;                             \
      const int cs = c_ ^ ((row >> 1) & 3);                                   \
      gload16(Vb + (size_t)row * 2048 + (tile) * 32 + cs * 8,                 \
              &V3[buf][chunk * 8]);                                           \
    }                                                                         \
  }
#define PV_LAG(par, vbuf)                                                     \
  {                                                                           \
    bf16x8 pfr0 = *(const bf16x8*)&P_lds[par][pr][0][l15][lg * 8];            \
    bf16x8 pfr1 = *(const bf16x8*)&P_lds[par][pr][1][l15][lg * 8];            \
    _Pragma("unroll") for (int dtile = 0; dtile < 16; ++dtile) {              \
      const int drow = whalf * 256 + dtile * 16 + l15;                        \
      const int pos = lg ^ ((drow >> 1) & 3);                                 \
      bf16x8 vf = *(const bf16x8*)&V3[vbuf][drow * 32 + pos * 8];             \
      acc[0][dtile] = mfma16(vf, pfr0, acc[0][dtile]);                        \
      acc[1][dtile] = mfma16(vf, pfr1, acc[1][dtile]);                        \
    }                                                                         \
  }

  STAGE_K8(0, 0);
  STAGE_V(0, 0);
  asm volatile("s_waitcnt vmcnt(0)" ::: "memory");
  __builtin_amdgcn_s_barrier();

  int vstage = 1;
  int vread = 2;

  for (int t = 0; t < 64; ++t) {
    const int cur = t & 1;

    if (t < 63) {
      STAGE_K8(t + 1, cur ^ 1);
      STAGE_V(t + 1, vstage);
    }

    f32x4 s0a = {}, s0b = {}, s1a = {}, s1b = {};
    {
      const u8* kbase = &K8[cur][krow * 512 + (lg & 1) * 8];
      const int phalf = lg >> 1;
#pragma unroll
      for (int cc = 0; cc < 8; ++cc) {
        const int p = (cc * 2 + phalf) ^ kswz;
        i64 kf = *(const i64*)(kbase + p * 16);
        s0a = mfma16f8(kf, qf8[0][cc], s0a);
        s1a = mfma16f8(kf, qf8[1][cc], s1a);
      }
#pragma unroll
      for (int cc = 8; cc < 16; ++cc) {
        const int p = (cc * 2 + phalf) ^ kswz;
        i64 kf = *(const i64*)(kbase + p * 16);
        s0b = mfma16f8(kf, qf8[0][cc], s0b);
        s1b = mfma16f8(kf, qf8[1][cc], s1b);
      }
    }
    f32x4 s0, s1;
#pragma unroll
    for (int r = 0; r < 4; ++r) {
      s0[r] = __expf(s0a[r] + s0b[r]);
      lsum0 += s0[r];
      s1[r] = __expf(s1a[r] + s1b[r]);
      lsum1 += s1[r];
    }

    {
      const int kvbase = whalf * 16 + lg * 4;
      u32 a0 = cvtpk(s0[0], s0[1]), a1 = cvtpk(s0[2], s0[3]);
      u32 b0 = cvtpk(s1[0], s1[1]), b1 = cvtpk(s1[2], s1[3]);
      u16x4 pk0 = __builtin_bit_cast(u16x4, ((unsigned long long)a1 << 32) | a0);
      u16x4 pk1 = __builtin_bit_cast(u16x4, ((unsigned long long)b1 << 32) | b0);
      *(u16x4*)&P_lds[cur][pr][0][l15][kvbase] = pk0;
      *(u16x4*)&P_lds[cur][pr][1][l15][kvbase] = pk1;
    }

    if (t > 0) PV_LAG(cur ^ 1, vread);

    asm volatile("s_waitcnt vmcnt(0) lgkmcnt(0)" ::: "memory");
    __builtin_amdgcn_s_barrier();

    vstage = (vstage == 2) ? 0 : vstage + 1;
    vread = (vread == 2) ? 0 : vread + 1;
  }

  PV_LAG(1, vread);

  lsum0 += __shfl_xor(lsum0, 16, 64);
  lsum0 += __shfl_xor(lsum0, 32, 64);
  lsum1 += __shfl_xor(lsum1, 16, 64);
  lsum1 += __shfl_xor(lsum1, 32, 64);
  if (lane < 16) {
    Lsum[w][0][l15] = lsum0;
    Lsum[w][1][l15] = lsum1;
  }
  __syncthreads();
  const float inv0 = 1.0f / (Lsum[w][0][l15] + Lsum[w ^ 1][0][l15]);
  const float inv1 = 1.0f / (Lsum[w][1][l15] + Lsum[w ^ 1][1][l15]);

  const int bb = bh >> 3, h = bh & 7;
#pragma unroll
  for (int qtile = 0; qtile < 2; ++qtile) {
    const float inv = qtile ? inv1 : inv0;
    const int q = qt * 128 + pr * 32 + qtile * 16 + l15;
    u16* orow_p = Og + (size_t)(bb * 2048 + q) * 4096 + h * 512 + whalf * 256;
#pragma unroll
    for (int dtile = 0; dtile < 16; ++dtile) {
      u16x4 pk;
#pragma unroll
      for (int r = 0; r < 4; ++r) pk[r] = f2bf(acc[qtile][dtile][r] * inv);
      *(u16x4*)(orow_p + dtile * 16 + lg * 4) = pk;
    }
  }
#undef STAGE_K8
#undef STAGE_V
#undef PV_LAG
}

// ---------------- launcher ----------------
// Per-batch: Q 8 + K 8 + Vt 16 + Og 16 = 48 MB.  ws need = 24 + 48*BB:
// BB=4 -> 216 MB, BB=2 -> 120 MB, BB=1 -> 72 MB.

extern "C" void kernel_launch(void* const* d_in, const int* in_sizes, int n_in,
                              void* d_out, int out_size, void* d_ws, size_t ws_size,
                              hipStream_t stream) {
  const float* x = (const float*)d_in[0];
  const float* Wq = (const float*)d_in[1];
  const float* Wk = (const float*)d_in[2];
  const float* Wv = (const float*)d_in[3];
  const float* Wo = (const float*)d_in[4];
  const float* bo = (const float*)d_in[5];
  float* out = (float*)d_out;

  const size_t MB = 1ull << 20;
  int BB;
  if (ws_size >= 216 * MB) BB = 4;
  else if (ws_size >= 120 * MB) BB = 2;
  else BB = 1;

  char* ws = (char*)d_ws;
  u16* xb  = (u16*)(ws);
  u16* Wqp = (u16*)(ws + 8 * MB);
  u16* Wkp = (u16*)(ws + 12 * MB);
  u16* Wvp = (u16*)(ws + 16 * MB);
  u16* Wot = (u16*)(ws + 20 * MB);
  u8*  Qg  = (u8*)(ws + 24 * MB);
  u8*  Kg  = (u8*)(ws + (24 + 8 * (size_t)BB) * MB);
  u16* Vtg = (u16*)(ws + (24 + 16 * (size_t)BB) * MB);
  u16* Og  = (u16*)(ws + (24 + 32 * (size_t)BB) * MB);

  pack_x_kernel<<<dim3(4096), dim3(256), 0, stream>>>(x, xb);
  pack_wqkv_t<<<dim3(64, 8), dim3(256), 0, stream>>>(Wq, Wqp);
  pack_wqkv_t<<<dim3(64, 8), dim3(256), 0, stream>>>(Wk, Wkp);
  pack_wqkv_t<<<dim3(64, 8), dim3(256), 0, stream>>>(Wv, Wvp);
  pack_wo_t<<<dim3(64, 8), dim3(256), 0, stream>>>(Wo, Wot);

  const float qk_scale = 0.21022410381342865f;  // 1 / 512^0.25

  const int nchunk = 4 / BB;
  for (int c = 0; c < nchunk; ++c) {
    const u16* Ax = xb + (size_t)c * BB * 2048 * 512;
    const int nwg_p = 32 * BB * 16;  // proj GEMM grid (1D), % 8 == 0
    const int nwg_o = 8 * BB * 16;   // out  GEMM grid (1D), % 8 == 0
    gemm_bf16<0, 128><<<dim3(nwg_p), dim3(256), 0, stream>>>(Ax, Wqp, (void*)Qg, nullptr, 512, qk_scale, 32);
    gemm_bf16<0, 128><<<dim3(nwg_p), dim3(256), 0, stream>>>(Ax, Wkp, (void*)Kg, nullptr, 512, qk_scale, 32);
    gemm_bf16<1, 128><<<dim3(nwg_p), dim3(256), 0, stream>>>(Ax, Wvp, (void*)Vtg, nullptr, 512, 1.0f, 32);

    attn_kernel<<<dim3(16 * BB * 8), dim3(512), 0, stream>>>(Qg, Kg, Vtg, Og, BB);

    gemm_bf16<2, 64><<<dim3(nwg_o), dim3(256), 0, stream>>>(
        Og, Wot, (void*)(out + (size_t)c * BB * 2048 * 512), bo, 4096, 1.0f, 8);
  }
}